// Round 1
// baseline (117.337 us; speedup 1.0000x reference)
//
#include <hip/hip_runtime.h>

#define DEV __device__ __forceinline__

typedef _Float16 half8 __attribute__((ext_vector_type(8)));
typedef float f32x16 __attribute__((ext_vector_type(16)));
typedef int int4v __attribute__((ext_vector_type(4)));

DEV f32x16 mfma16(half8 a, half8 b, f32x16 c) {
    return __builtin_amdgcn_mfma_f32_32x32x16_f16(a, b, c, 0, 0, 0);
}
DEV half8 h8(int4v v) { return __builtin_bit_cast(half8, v); }
DEV int pkrtz(float a, float b) {
    auto t = __builtin_amdgcn_cvt_pkrtz(a, b);  // v_cvt_pkrtz_f16_f32 -> 2x f16 packed
    return __builtin_bit_cast(int, t);
}
// v_permlane32_swap_b32: a[32..63] <-> b[0..31]
DEV void plswap(int& a, int& b) {
    asm("v_permlane32_swap_b32 %0, %1" : "+v"(a), "+v"(b));
}

struct Frags { int4v c[4]; };  // activation B-fragments, K=64 (4 chunks of 16)

DEV int4v bias_frag(float bv, int h) {
    // A_bias[row][k]: only k==0 nonzero -> lane-half h==0, element e==0
    int lo = pkrtz(bv, 0.f);
    int4v r;
    r[0] = (h == 0) ? lo : 0; r[1] = 0; r[2] = 0; r[3] = 0;
    return r;
}

// One layer for one 32-row tile: C[m] = bias + sum_kk A[m][kk]*B[kk]; relu; repack to next B-frags.
template<int NC>
DEV void proc_tile(const half8* A0, const half8* A1, int4v ab0, int4v ab1, int4v ones, Frags& B) {
    f32x16 z = {0.f,0.f,0.f,0.f,0.f,0.f,0.f,0.f,0.f,0.f,0.f,0.f,0.f,0.f,0.f,0.f};
    f32x16 C0 = mfma16(h8(ab0), h8(ones), z);
    f32x16 C1 = mfma16(h8(ab1), h8(ones), z);
#pragma unroll
    for (int kk = 0; kk < NC; ++kk) {
        half8 bf = h8(B.c[kk]);
        C0 = mfma16(A0[kk], bf, C0);
        C1 = mfma16(A1[kk], bf, C1);
    }
    // relu + pack pairs: P[q] = f16x2(feat(2q), feat(2q)+1), feat(r)=(r&3)+8*(r>>2)+4h (+32 for C1)
    int P0[8], P1[8];
#pragma unroll
    for (int q = 0; q < 8; ++q) {
        P0[q] = pkrtz(fmaxf(C0[2*q], 0.f), fmaxf(C0[2*q+1], 0.f));
        P1[q] = pkrtz(fmaxf(C1[2*q], 0.f), fmaxf(C1[2*q+1], 0.f));
    }
    // chunk kk covers features [16kk,16kk+16): regs 4*(kk&1).. of M-tile kk>>1
#pragma unroll
    for (int kk = 0; kk < 4; ++kk) {
        const int* Pm = (kk < 2) ? P0 : P1;
        int idx = 4 * (kk & 1);
        int a0 = Pm[idx + 0], b0 = Pm[idx + 2];
        int a1 = Pm[idx + 1], b1 = Pm[idx + 3];
        plswap(a0, b0);  // -> a0=e01, b0=e45
        plswap(a1, b1);  // -> a1=e23, b1=e67
        int4v nb; nb[0] = a0; nb[1] = a1; nb[2] = b0; nb[3] = b1;
        B.c[kk] = nb;
    }
}

template<int NC>
DEV void layer_step(const _Float16* wb, const float* bp, int lam, int4v ones, Frags& B0, Frags& B1) {
    const int col = lam & 31, h = lam >> 5;
    half8 A0[NC], A1[NC];
#pragma unroll
    for (int kk = 0; kk < NC; ++kk) {
        A0[kk] = *(const half8*)(wb + kk * 512 + lam * 8);
        A1[kk] = *(const half8*)(wb + NC * 512 + kk * 512 + lam * 8);
    }
    int4v ab0 = bias_frag(bp[col], h);
    int4v ab1 = bias_frag(bp[32 + col], h);
    proc_tile<NC>(A0, A1, ab0, ab1, ones, B0);
    proc_tile<NC>(A0, A1, ab0, ab1, ones, B1);
}

DEV void out_step(const _Float16* wb, const float* bp, int lam, int4v ones,
                  const Frags& B, float* __restrict__ out, int row) {
    const int col = lam & 31, h = lam >> 5;
    half8 A[4];
#pragma unroll
    for (int kk = 0; kk < 4; ++kk) A[kk] = *(const half8*)(wb + kk * 512 + lam * 8);
    int4v ab = bias_frag(bp[col], h);
    f32x16 z = {0.f,0.f,0.f,0.f,0.f,0.f,0.f,0.f,0.f,0.f,0.f,0.f,0.f,0.f,0.f,0.f};
    f32x16 C = mfma16(h8(ab), h8(ones), z);
#pragma unroll
    for (int kk = 0; kk < 4; ++kk) C = mfma16(A[kk], h8(B.c[kk]), C);
    float* orow = out + row * 21;
#pragma unroll
    for (int r = 0; r < 16; ++r) {
        int f = (r & 3) + 8 * (r >> 2) + 4 * h;
        if (f < 21) orow[f] = __builtin_amdgcn_rcpf(1.f + __expf(-C[r]));
    }
}

DEV void load_x(const float* __restrict__ x, int row, int h, Frags& B) {
    // B-frag: col=lane&31=row-in-tile, k = 16*kk + 8*h + e ; x row stride 28 f32 = 112B (16B aligned)
    const float* xr = x + row * 28;
    float4 fa = *(const float4*)(xr + 8 * h);
    float4 fb = *(const float4*)(xr + 8 * h + 4);
    float4 fc = *(const float4*)(xr + 16 + 8 * h);
    float4 fd = make_float4(0.f, 0.f, 0.f, 0.f);
    if (h == 0) fd = *(const float4*)(xr + 20);  // h==1 slots are features 28..31 -> zero pad
    int4v c0, c1;
    c0[0] = pkrtz(fa.x, fa.y); c0[1] = pkrtz(fa.z, fa.w);
    c0[2] = pkrtz(fb.x, fb.y); c0[3] = pkrtz(fb.z, fb.w);
    c1[0] = pkrtz(fc.x, fc.y); c1[1] = pkrtz(fc.z, fc.w);
    c1[2] = pkrtz(fd.x, fd.y); c1[3] = pkrtz(fd.z, fd.w);
    B.c[0] = c0; B.c[1] = c1;
}

__global__ __launch_bounds__(768) void mlp_fused(
    const float* __restrict__ x, const float* __restrict__ W_in, const float* __restrict__ b_in,
    const float* __restrict__ W_hid, const float* __restrict__ b_hid,
    const float* __restrict__ W_out, const float* __restrict__ b_out,
    float* __restrict__ out) {
    // LDS: weights in f16, pre-laid in A-fragment order: [m][kk][lane][e], A = W^T
    __shared__ __align__(16) _Float16 wH[40960];  // 10 x 64x64
    __shared__ __align__(16) _Float16 wI[2048];   // 32(pad28) x 64
    __shared__ __align__(16) _Float16 wO[2048];   // 64 x 32(pad21)
    __shared__ __align__(16) float bia[736];      // b_in[64] | b_hid[640] | b_out[32]

    const int tid = threadIdx.x;

    for (int i = tid; i < 2048; i += 768) { wI[i] = (_Float16)0.f; wO[i] = (_Float16)0.f; }
    __syncthreads();

    // coalesced global reads, scattered LDS writes
    for (int i = tid; i < 40960; i += 768) {
        int o = i & 63, kin = (i >> 6) & 63, l = i >> 12;
        int m = o >> 5, kk = kin >> 4, hh = (kin >> 3) & 1, e = kin & 7;
        int lam = hh * 32 + (o & 31);
        wH[l * 4096 + m * 2048 + kk * 512 + lam * 8 + e] = (_Float16)W_hid[i];
    }
    for (int i = tid; i < 1792; i += 768) {  // W_in [28][64]
        int o = i & 63, kin = i >> 6;
        int m = o >> 5, kk = kin >> 4, hh = (kin >> 3) & 1, e = kin & 7;
        int lam = hh * 32 + (o & 31);
        wI[m * 1024 + kk * 512 + lam * 8 + e] = (_Float16)W_in[i];
    }
    for (int i = tid; i < 1344; i += 768) {  // W_out [64][21]
        int o = i % 21, kin = i / 21;
        int kk = kin >> 4, hh = (kin >> 3) & 1, e = kin & 7;
        int lam = hh * 32 + o;
        wO[kk * 512 + lam * 8 + e] = (_Float16)W_out[i];
    }
    for (int i = tid; i < 64; i += 768) bia[i] = b_in[i];
    for (int i = tid; i < 640; i += 768) bia[64 + i] = b_hid[i];
    for (int i = tid; i < 32; i += 768) bia[704 + i] = (i < 21) ? b_out[i] : 0.f;
    __syncthreads();

    const int w = tid >> 6, lam = tid & 63;
    const int col = lam & 31, h = lam >> 5;
    int4v ones; ones[0] = (h == 0) ? 0x3C00 : 0; ones[1] = 0; ones[2] = 0; ones[3] = 0;

    // persistent: 256 blocks x 128 tiles; wave w takes pairs pb = w*2 + 24k  (16 pairs/SIMD, balanced)
    const int tbase = blockIdx.x * 128;
#pragma unroll 1
    for (int pb = w * 2; pb < 128; pb += 24) {
        int t0 = tbase + pb;
        int row0 = t0 * 32 + col, row1 = row0 + 32;
        Frags B0, B1;
        load_x(x, row0, h, B0);
        load_x(x, row1, h, B1);
        layer_step<2>(wI, bia, lam, ones, B0, B1);
#pragma unroll 1
        for (int l = 0; l < 10; ++l)
            layer_step<4>(wH + l * 4096, bia + 64 + l * 64, lam, ones, B0, B1);
        out_step(wO, bia + 704, lam, ones, B0, out, row0);
        out_step(wO, bia + 704, lam, ones, B1, out, row1);
    }
}

extern "C" void kernel_launch(void* const* d_in, const int* in_sizes, int n_in,
                              void* d_out, int out_size, void* d_ws, size_t ws_size,
                              hipStream_t stream) {
    const float* x     = (const float*)d_in[0];
    const float* W_in  = (const float*)d_in[1];
    const float* b_in  = (const float*)d_in[2];
    const float* W_hid = (const float*)d_in[3];
    const float* b_hid = (const float*)d_in[4];
    const float* W_out = (const float*)d_in[5];
    const float* b_out = (const float*)d_in[6];
    float* out = (float*)d_out;
    mlp_fused<<<dim3(256), dim3(768), 0, stream>>>(x, W_in, b_in, W_hid, b_hid, W_out, b_out, out);
}